// Round 19
// baseline (292.122 us; speedup 1.0000x reference)
//
#include <hip/hip_runtime.h>
#include <hip/hip_bf16.h>
#include <hip/hip_fp16.h>

typedef __attribute__((ext_vector_type(8))) short short8;
typedef __attribute__((ext_vector_type(8))) _Float16 f16x8;
typedef __attribute__((ext_vector_type(4))) float f32x4;

// ================= CSR build: fixed-capacity bins + per-block reservation =================
#define EPB 16384
#define CAP_SHIFT 13
#define CAP (1 << CAP_SHIFT)

__global__ __launch_bounds__(256) void k_fused_scatter(
    const int* __restrict__ src, const int* __restrict__ dst,
    int* __restrict__ binCursor, int* __restrict__ binned, int nE, int nbins) {
  __shared__ int c[1024];
  int tid = threadIdx.x;
  for (int i = tid; i < nbins; i += 256) c[i] = 0;
  __syncthreads();
  int e0 = blockIdx.x * EPB;
  int e1 = min(nE, e0 + EPB);
  if (e1 - e0 == EPB) {
#pragma unroll
    for (int it = 0; it < EPB / 1024; ++it) {
      int4 d = *(const int4*)(dst + e0 + it * 1024 + tid * 4);
      atomicAdd(&c[d.x >> 7], 1);
      atomicAdd(&c[d.y >> 7], 1);
      atomicAdd(&c[d.z >> 7], 1);
      atomicAdd(&c[d.w >> 7], 1);
    }
  } else {
    for (int i = e0 + tid; i < e1; i += 256) atomicAdd(&c[dst[i] >> 7], 1);
  }
  __syncthreads();
  for (int i = tid; i < nbins; i += 256) {
    int v = c[i];
    int base = v ? atomicAdd(&binCursor[i], v) : 0;
    c[i] = (i << CAP_SHIFT) + base;
  }
  __syncthreads();
  if (e1 - e0 == EPB) {
#pragma unroll
    for (int it = 0; it < EPB / 1024; ++it) {
      int base = e0 + it * 1024 + tid * 4;
      int4 s = *(const int4*)(src + base);
      int4 d = *(const int4*)(dst + base);
      int p0 = atomicAdd(&c[d.x >> 7], 1);
      int p1 = atomicAdd(&c[d.y >> 7], 1);
      int p2 = atomicAdd(&c[d.z >> 7], 1);
      int p3 = atomicAdd(&c[d.w >> 7], 1);
      binned[p0] = s.x | ((d.x & 127) << 20);
      binned[p1] = s.y | ((d.y & 127) << 20);
      binned[p2] = s.z | ((d.z & 127) << 20);
      binned[p3] = s.w | ((d.w & 127) << 20);
    }
  } else {
    for (int i = e0 + tid; i < e1; i += 256) {
      int d = dst[i];
      int pos = atomicAdd(&c[d >> 7], 1);
      binned[pos] = src[i] | ((d & 127) << 20);
    }
  }
}

// ---- fused bin finish: count -> LDS scan -> cnt/rowptr/dinv -> place ----

__global__ __launch_bounds__(256) void k_bin_finish(
    const int* __restrict__ binned, const int* __restrict__ binCnt,
    int* __restrict__ cnt, int* __restrict__ rowptr, float* __restrict__ dinv,
    int* __restrict__ col, int nbins, int n) {
  __shared__ int c128[128];
  __shared__ int scan128[128];
  __shared__ int cur128[128];
  int b = blockIdx.x;
  int tid = threadIdx.x;
  if (tid < 128) c128[tid] = 0;
  __syncthreads();
  int s0 = b << CAP_SHIFT;
  int s1 = s0 + binCnt[b];
  for (int i = s0 + tid; i < s1; i += 256)
    atomicAdd(&c128[(binned[i] >> 20) & 127], 1);
  __syncthreads();
  if (tid < 128) scan128[tid] = c128[tid];
  __syncthreads();
  for (int off = 1; off < 128; off <<= 1) {
    int t = 0;
    if (tid < 128 && tid >= off) t = scan128[tid - off];
    __syncthreads();
    if (tid < 128) scan128[tid] += t;
    __syncthreads();
  }
  if (tid < 128) {
    int v = c128[tid];
    int rp = s0 + scan128[tid] - v;
    int idx = (b << 7) + tid;
    if (idx < n) {
      cnt[idx] = v;
      rowptr[idx] = rp;
      dinv[idx] = rsqrtf((float)(v + 1));  // +1 self-loop
    }
    cur128[tid] = rp;
  }
  __syncthreads();
  for (int i = s0 + tid; i < s1; i += 256) {
    int e = binned[i];
    int pos = atomicAdd(&cur128[(e >> 20) & 127], 1);
    col[pos] = e & 0xFFFFF;
  }
}

// ---- weight prep: fp16 + transpose; fuse Wmu|Wls, bmu|bls ----

__global__ void k_prep_w(const float* __restrict__ W1,
                         const float* __restrict__ Wmu, const float* __restrict__ Wls,
                         const float* __restrict__ bmu, const float* __restrict__ bls,
                         __half* __restrict__ W1T, __half* __restrict__ WcT,
                         float* __restrict__ bcat) {
  int i = blockIdx.x * blockDim.x + threadIdx.x;
  if (i < 128 * 256) {                     // W1T [n][k]
    int n = i >> 8, k = i & 255;
    W1T[i] = __float2half(W1[k * 128 + n]);
  } else if (i < 2 * 128 * 256) {          // WcT [n][k]
    int j = i - 128 * 256;
    int n = j >> 7, k = j & 127;
    float f = (n < 128) ? Wmu[k * 128 + n] : Wls[k * 128 + (n - 128)];
    WcT[j] = __float2half(f);
  } else if (i < 2 * 128 * 256 + 256) {    // bcat
    int n = i - 2 * 128 * 256;
    bcat[n] = (n < 128) ? bmu[n] : bls[n - 128];
  }
}

// ---------------- MFMA GEMM (8-wave round-10 skeleton) — GEMM1 ----------------

#define LP 40  // LDS row stride in halves

__global__ __launch_bounds__(512) void k_gemm_mfma(
    const float* __restrict__ Av, const __half* __restrict__ WT,
    __half* __restrict__ out0, int M, int K) {
  __shared__ _Float16 As[128 * LP];
  __shared__ _Float16 Bs[128 * LP];

  const int tid = threadIdx.x;
  const int lane = tid & 63;
  const int wv = tid >> 6;                 // 0..7
  const int wr = wv >> 2, wc = wv & 3;     // 2 x 4 waves
  const int rsel = lane >> 4;
  const int rrow = lane & 15;
  const int row0 = blockIdx.x * 128;

  f32x4 acc[4][2];
#pragma unroll
  for (int m = 0; m < 4; m++)
#pragma unroll
    for (int n = 0; n < 2; n++) acc[m][n] = (f32x4){0.f, 0.f, 0.f, 0.f};

  const int srow = tid >> 2;               // 0..127
  const int skh = (tid & 3) * 8;           // 0,8,16,24

  for (int k0 = 0; k0 < K; k0 += 32) {
    if (row0 + srow < M) {
      const float* src = Av + (size_t)(row0 + srow) * K + k0 + skh;
      float4 f0 = *(const float4*)(src);
      float4 f1 = *(const float4*)(src + 4);
      f16x8 v0;
      v0[0]=(_Float16)f0.x; v0[1]=(_Float16)f0.y; v0[2]=(_Float16)f0.z; v0[3]=(_Float16)f0.w;
      v0[4]=(_Float16)f1.x; v0[5]=(_Float16)f1.y; v0[6]=(_Float16)f1.z; v0[7]=(_Float16)f1.w;
      *(f16x8*)&As[srow * LP + skh] = v0;
    } else {
      *(f16x8*)&As[srow * LP + skh] = (f16x8){0,0,0,0,0,0,0,0};
    }
    *(f16x8*)&Bs[srow * LP + skh] =
        *(const f16x8*)((const _Float16*)WT + (size_t)srow * K + k0 + skh);
    __syncthreads();

    f16x8 fa[4], fb[2];
#pragma unroll
    for (int m = 0; m < 4; m++)
      fa[m] = *(f16x8*)&As[(wr * 64 + m * 16 + rrow) * LP + rsel * 8];
#pragma unroll
    for (int n = 0; n < 2; n++)
      fb[n] = *(f16x8*)&Bs[(wc * 32 + n * 16 + rrow) * LP + rsel * 8];
#pragma unroll
    for (int m = 0; m < 4; m++)
#pragma unroll
      for (int n = 0; n < 2; n++)
        acc[m][n] = __builtin_amdgcn_mfma_f32_16x16x32_f16(fa[m], fb[n], acc[m][n], 0, 0, 0);
    __syncthreads();
  }

#pragma unroll
  for (int n = 0; n < 2; n++) {
    int c = wc * 32 + n * 16 + rrow;
#pragma unroll
    for (int m = 0; m < 4; m++) {
      f32x4 v = acc[m][n];
#pragma unroll
      for (int r = 0; r < 4; r++) {
        int row = row0 + wr * 64 + m * 16 + rsel * 4 + r;
        if (row < M) out0[(size_t)row * 128 + c] = __float2half(v[r]);
      }
    }
  }
}

// ---------------- pull-based SpMM (fp16 rows, on-the-fly norm) ----------------

__global__ __launch_bounds__(256) void k_spmm_h(
    const __half* __restrict__ in, const int* __restrict__ rowptr,
    const int* __restrict__ cnt, const int* __restrict__ col,
    const float* __restrict__ dinv,
    const float* __restrict__ bias, __half* __restrict__ out,
    int n, int use_bias, int relu_out) {
  int node = blockIdx.x * 4 + (threadIdx.x >> 6);
  if (node >= n) return;
  int lane = threadIdx.x & 63;

  const __half2* inp = (const __half2*)in;
  float di = dinv[node];
  float2 v = __half22float2(inp[(size_t)node * 64 + lane]);
  float accx = di * v.x;
  float accy = di * v.y;

  int beg = rowptr[node];
  int m = cnt[node];
  int i = 0;
  for (; i + 8 <= m; i += 8) {
    int c[8];
#pragma unroll
    for (int j = 0; j < 8; j++) c[j] = col[beg + i + j];
    float e[8];
#pragma unroll
    for (int j = 0; j < 8; j++) e[j] = dinv[c[j]];
    float2 u[8];
#pragma unroll
    for (int j = 0; j < 8; j++) u[j] = __half22float2(inp[(size_t)c[j] * 64 + lane]);
#pragma unroll
    for (int j = 0; j < 8; j++) { accx += e[j] * u[j].x; accy += e[j] * u[j].y; }
  }
  if (i < m) {
    int c[8];
#pragma unroll
    for (int j = 0; j < 8; j++) c[j] = col[(i + j < m) ? (beg + i + j) : beg];
    float e[8];
#pragma unroll
    for (int j = 0; j < 8; j++) e[j] = (i + j < m) ? dinv[c[j]] : 0.f;
    float2 u[8];
#pragma unroll
    for (int j = 0; j < 8; j++) u[j] = __half22float2(inp[(size_t)c[j] * 64 + lane]);
#pragma unroll
    for (int j = 0; j < 8; j++) { accx += e[j] * u[j].x; accy += e[j] * u[j].y; }
  }
  accx *= di;
  accy *= di;
  if (use_bias) {
    accx += bias[2 * lane];
    accy += bias[2 * lane + 1];
  }
  if (relu_out) {
    accx = fmaxf(accx, 0.f);
    accy = fmaxf(accy, 0.f);
  }
  ((__half2*)(out + (size_t)node * 128))[lane] = __floats2half2_rn(accx, accy);
}

// ---------------- fused SpMM2 + GEMM2: 16 waves, ONE node per wave ----------------
// Block = 16 nodes, 1024 thr = 16 waves. Phase 1 parallelism == k_spmm_h (1 node/wave).
// Phase 2: wave w computes col-tile w (16 cols) of the 16x256 output.

__global__ __launch_bounds__(1024) void k_spmm_gemm(
    const __half* __restrict__ in, const int* __restrict__ rowptr,
    const int* __restrict__ cnt, const int* __restrict__ col,
    const float* __restrict__ dinv,
    const __half* __restrict__ WcT, const float* __restrict__ bcat,
    float* __restrict__ out0, float* __restrict__ out1, int n) {
  __shared__ _Float16 gt[16 * 128];   // 16 rows x 256B, 16B-chunk XOR-swizzled by row
  const int tid = threadIdx.x;
  const int lane = tid & 63;
  const int w = tid >> 6;             // 0..15 — node index AND col-tile index
  const __half2* inp = (const __half2*)in;

  // ---- phase 1: one g-row per wave ----
  {
    int node = blockIdx.x * 16 + w;
    float accx = 0.f, accy = 0.f;
    if (node < n) {
      float di = dinv[node];
      float2 v = __half22float2(inp[(size_t)node * 64 + lane]);
      accx = di * v.x;
      accy = di * v.y;
      int beg = rowptr[node];
      int m = cnt[node];
      int i = 0;
      for (; i + 8 <= m; i += 8) {
        int c[8];
#pragma unroll
        for (int j = 0; j < 8; j++) c[j] = col[beg + i + j];
        float e[8];
#pragma unroll
        for (int j = 0; j < 8; j++) e[j] = dinv[c[j]];
        float2 u[8];
#pragma unroll
        for (int j = 0; j < 8; j++) u[j] = __half22float2(inp[(size_t)c[j] * 64 + lane]);
#pragma unroll
        for (int j = 0; j < 8; j++) { accx += e[j] * u[j].x; accy += e[j] * u[j].y; }
      }
      if (i < m) {
        int c[8];
#pragma unroll
        for (int j = 0; j < 8; j++) c[j] = col[(i + j < m) ? (beg + i + j) : beg];
        float e[8];
#pragma unroll
        for (int j = 0; j < 8; j++) e[j] = (i + j < m) ? dinv[c[j]] : 0.f;
        float2 u[8];
#pragma unroll
        for (int j = 0; j < 8; j++) u[j] = __half22float2(inp[(size_t)c[j] * 64 + lane]);
#pragma unroll
        for (int j = 0; j < 8; j++) { accx += e[j] * u[j].x; accy += e[j] * u[j].y; }
      }
      accx *= di;
      accy *= di;
    }
    int slot = (lane >> 2) ^ (w & 7);
    *(__half2*)((char*)gt + w * 256 + slot * 16 + (lane & 3) * 4) =
        __floats2half2_rn(accx, accy);
  }
  __syncthreads();

  // ---- phase 2: wave w -> col-tile w (16 cols), 4 MFMAs over K=128 ----
  const int lr = lane & 15;
  const int lk = lane >> 4;
  f16x8 a[4];
#pragma unroll
  for (int ks = 0; ks < 4; ks++) {
    int slot = (ks * 4 + lk) ^ (lr & 7);
    a[ks] = *(const f16x8*)((const char*)gt + lr * 256 + slot * 16);
  }
  {
    int colg = w * 16 + lr;               // 0..255
    f32x4 acc = (f32x4){0.f, 0.f, 0.f, 0.f};
#pragma unroll
    for (int ks = 0; ks < 4; ks++) {
      f16x8 b = *(const f16x8*)((const _Float16*)WcT + (size_t)colg * 128 + ks * 32 + lk * 8);
      acc = __builtin_amdgcn_mfma_f32_16x16x32_f16(a[ks], b, acc, 0, 0, 0);
    }
    float badd = bcat[colg];
    float* dst = out0;
    int c = colg;
    if (c >= 128) { dst = out1; c -= 128; }
#pragma unroll
    for (int r = 0; r < 4; r++) {
      int node = blockIdx.x * 16 + lk * 4 + r;
      if (node < n) dst[(size_t)node * 128 + c] = acc[r] + badd;
    }
  }
}

// ---------------- launch ----------------

extern "C" void kernel_launch(void* const* d_in, const int* in_sizes, int n_in,
                              void* d_out, int out_size, void* d_ws, size_t ws_size,
                              hipStream_t stream) {
  const float* x   = (const float*)d_in[0];
  const int*   ei  = (const int*)d_in[1];
  const float* W1  = (const float*)d_in[2];
  const float* b1  = (const float*)d_in[3];
  const float* Wmu = (const float*)d_in[4];
  const float* bmu = (const float*)d_in[5];
  const float* Wls = (const float*)d_in[6];
  const float* bls = (const float*)d_in[7];

  int N = in_sizes[0] / 256;
  int E = in_sizes[1] / 2;
  const int* src = ei;
  const int* dst = ei + E;

  int NBINS = (N + 127) >> 7;
  int NBLK  = (E + EPB - 1) / EPB;

  char* ws = (char*)d_ws;
  size_t o = 0;
  auto alloc = [&](size_t b) { size_t c = o; o = (o + b + 511) & ~(size_t)511; return c; };
  int*   cnt       = (int*)(ws + alloc((size_t)N * 4));
  int*   rowptr    = (int*)(ws + alloc((size_t)N * 4));
  float* dinv      = (float*)(ws + alloc((size_t)N * 4));
  int*   binCursor = (int*)(ws + alloc((size_t)NBINS * 4));
  int*   col       = (int*)(ws + alloc((size_t)NBINS * CAP * 4));
  int*   binned    = (int*)(ws + alloc((size_t)NBINS * CAP * 4));
  __half* W1T  = (__half*)(ws + alloc(128 * 256 * 2));
  __half* WcT  = (__half*)(ws + alloc(256 * 128 * 2));
  float*  bcat = (float*)(ws + alloc(256 * 4));
  __half* h0   = (__half*)(ws + alloc((size_t)N * 128 * 2));  // GEMM1 out
  __half* hBuf = (__half*)(ws + alloc((size_t)N * 128 * 2));  // h (relu'd)

  float* outMu = (float*)d_out;
  float* outLs = outMu + (size_t)N * 128;

  // ---- CSR build: reserve-scatter -> fused bin-finish ----
  hipMemsetAsync(binCursor, 0, (size_t)NBINS * 4, stream);
  k_fused_scatter<<<NBLK, 256, 0, stream>>>(src, dst, binCursor, binned, E, NBINS);
  k_bin_finish<<<NBINS, 256, 0, stream>>>(binned, binCursor, cnt, rowptr, dinv, col,
                                          NBINS, N);

  // ---- weights ----
  k_prep_w<<<(2 * 128 * 256 + 256 + 255) / 256, 256, 0, stream>>>(
      W1, Wmu, Wls, bmu, bls, W1T, WcT, bcat);

  // h0 = x @ W1                 [N,128] fp16 (8-wave round-10 skeleton)
  k_gemm_mfma<<<(N + 127) / 128, 512, 0, stream>>>(x, W1T, h0, N, 256);
  // h = relu(A h0 + b1)         [N,128] fp16
  k_spmm_h<<<(N + 3) / 4, 256, 0, stream>>>(h0, rowptr, cnt, col, dinv, b1, hBuf, N, 1, 1);
  // [mu|ls] = (A h) @ [Wmu|Wls] + [bmu|bls]   fused, 16 waves / 1 node per wave
  k_spmm_gemm<<<(N + 15) / 16, 1024, 0, stream>>>(
      hBuf, rowptr, cnt, col, dinv, WcT, bcat, outMu, outLs, N);
}

// Round 20
// 284.019 us; speedup vs baseline: 1.0285x; 1.0285x over previous
//
#include <hip/hip_runtime.h>
#include <hip/hip_bf16.h>
#include <hip/hip_fp16.h>

typedef __attribute__((ext_vector_type(8))) short short8;
typedef __attribute__((ext_vector_type(8))) _Float16 f16x8;
typedef __attribute__((ext_vector_type(4))) float f32x4;

// ================= CSR build: fixed-capacity bins + per-block reservation =================
#define EPB 16384
#define CAP_SHIFT 13
#define CAP (1 << CAP_SHIFT)

__global__ __launch_bounds__(256) void k_fused_scatter(
    const int* __restrict__ src, const int* __restrict__ dst,
    int* __restrict__ binCursor, int* __restrict__ binned, int nE, int nbins) {
  __shared__ int c[1024];
  int tid = threadIdx.x;
  for (int i = tid; i < nbins; i += 256) c[i] = 0;
  __syncthreads();
  int e0 = blockIdx.x * EPB;
  int e1 = min(nE, e0 + EPB);
  if (e1 - e0 == EPB) {
#pragma unroll
    for (int it = 0; it < EPB / 1024; ++it) {
      int4 d = *(const int4*)(dst + e0 + it * 1024 + tid * 4);
      atomicAdd(&c[d.x >> 7], 1);
      atomicAdd(&c[d.y >> 7], 1);
      atomicAdd(&c[d.z >> 7], 1);
      atomicAdd(&c[d.w >> 7], 1);
    }
  } else {
    for (int i = e0 + tid; i < e1; i += 256) atomicAdd(&c[dst[i] >> 7], 1);
  }
  __syncthreads();
  for (int i = tid; i < nbins; i += 256) {
    int v = c[i];
    int base = v ? atomicAdd(&binCursor[i], v) : 0;
    c[i] = (i << CAP_SHIFT) + base;
  }
  __syncthreads();
  if (e1 - e0 == EPB) {
#pragma unroll
    for (int it = 0; it < EPB / 1024; ++it) {
      int base = e0 + it * 1024 + tid * 4;
      int4 s = *(const int4*)(src + base);
      int4 d = *(const int4*)(dst + base);
      int p0 = atomicAdd(&c[d.x >> 7], 1);
      int p1 = atomicAdd(&c[d.y >> 7], 1);
      int p2 = atomicAdd(&c[d.z >> 7], 1);
      int p3 = atomicAdd(&c[d.w >> 7], 1);
      binned[p0] = s.x | ((d.x & 127) << 20);
      binned[p1] = s.y | ((d.y & 127) << 20);
      binned[p2] = s.z | ((d.z & 127) << 20);
      binned[p3] = s.w | ((d.w & 127) << 20);
    }
  } else {
    for (int i = e0 + tid; i < e1; i += 256) {
      int d = dst[i];
      int pos = atomicAdd(&c[d >> 7], 1);
      binned[pos] = src[i] | ((d & 127) << 20);
    }
  }
}

// ---- fused bin finish: count -> LDS scan -> cnt/rowptr/dinv -> place ----

__global__ __launch_bounds__(256) void k_bin_finish(
    const int* __restrict__ binned, const int* __restrict__ binCnt,
    int* __restrict__ cnt, int* __restrict__ rowptr, float* __restrict__ dinv,
    int* __restrict__ col, int nbins, int n) {
  __shared__ int c128[128];
  __shared__ int scan128[128];
  __shared__ int cur128[128];
  int b = blockIdx.x;
  int tid = threadIdx.x;
  if (tid < 128) c128[tid] = 0;
  __syncthreads();
  int s0 = b << CAP_SHIFT;
  int s1 = s0 + binCnt[b];
  for (int i = s0 + tid; i < s1; i += 256)
    atomicAdd(&c128[(binned[i] >> 20) & 127], 1);
  __syncthreads();
  if (tid < 128) scan128[tid] = c128[tid];
  __syncthreads();
  for (int off = 1; off < 128; off <<= 1) {
    int t = 0;
    if (tid < 128 && tid >= off) t = scan128[tid - off];
    __syncthreads();
    if (tid < 128) scan128[tid] += t;
    __syncthreads();
  }
  if (tid < 128) {
    int v = c128[tid];
    int rp = s0 + scan128[tid] - v;
    int idx = (b << 7) + tid;
    if (idx < n) {
      cnt[idx] = v;
      rowptr[idx] = rp;
      dinv[idx] = rsqrtf((float)(v + 1));  // +1 self-loop
    }
    cur128[tid] = rp;
  }
  __syncthreads();
  for (int i = s0 + tid; i < s1; i += 256) {
    int e = binned[i];
    int pos = atomicAdd(&cur128[(e >> 20) & 127], 1);
    col[pos] = e & 0xFFFFF;
  }
}

// ---- weight prep: fp16 + transpose; fuse Wmu|Wls, bmu|bls ----

__global__ void k_prep_w(const float* __restrict__ W1,
                         const float* __restrict__ Wmu, const float* __restrict__ Wls,
                         const float* __restrict__ bmu, const float* __restrict__ bls,
                         __half* __restrict__ W1T, __half* __restrict__ WcT,
                         float* __restrict__ bcat) {
  int i = blockIdx.x * blockDim.x + threadIdx.x;
  if (i < 128 * 256) {                     // W1T [n][k]
    int n = i >> 8, k = i & 255;
    W1T[i] = __float2half(W1[k * 128 + n]);
  } else if (i < 2 * 128 * 256) {          // WcT [n][k]
    int j = i - 128 * 256;
    int n = j >> 7, k = j & 127;
    float f = (n < 128) ? Wmu[k * 128 + n] : Wls[k * 128 + (n - 128)];
    WcT[j] = __float2half(f);
  } else if (i < 2 * 128 * 256 + 256) {    // bcat
    int n = i - 2 * 128 * 256;
    bcat[n] = (n < 128) ? bmu[n] : bls[n - 128];
  }
}

// ---------------- MFMA GEMM (8-wave round-10 skeleton) — GEMM1 ----------------

#define LP 40  // LDS row stride in halves

__global__ __launch_bounds__(512) void k_gemm_mfma(
    const float* __restrict__ Av, const __half* __restrict__ WT,
    __half* __restrict__ out0, int M, int K) {
  __shared__ _Float16 As[128 * LP];
  __shared__ _Float16 Bs[128 * LP];

  const int tid = threadIdx.x;
  const int lane = tid & 63;
  const int wv = tid >> 6;                 // 0..7
  const int wr = wv >> 2, wc = wv & 3;     // 2 x 4 waves
  const int rsel = lane >> 4;
  const int rrow = lane & 15;
  const int row0 = blockIdx.x * 128;

  f32x4 acc[4][2];
#pragma unroll
  for (int m = 0; m < 4; m++)
#pragma unroll
    for (int n = 0; n < 2; n++) acc[m][n] = (f32x4){0.f, 0.f, 0.f, 0.f};

  const int srow = tid >> 2;               // 0..127
  const int skh = (tid & 3) * 8;           // 0,8,16,24

  for (int k0 = 0; k0 < K; k0 += 32) {
    if (row0 + srow < M) {
      const float* src = Av + (size_t)(row0 + srow) * K + k0 + skh;
      float4 f0 = *(const float4*)(src);
      float4 f1 = *(const float4*)(src + 4);
      f16x8 v0;
      v0[0]=(_Float16)f0.x; v0[1]=(_Float16)f0.y; v0[2]=(_Float16)f0.z; v0[3]=(_Float16)f0.w;
      v0[4]=(_Float16)f1.x; v0[5]=(_Float16)f1.y; v0[6]=(_Float16)f1.z; v0[7]=(_Float16)f1.w;
      *(f16x8*)&As[srow * LP + skh] = v0;
    } else {
      *(f16x8*)&As[srow * LP + skh] = (f16x8){0,0,0,0,0,0,0,0};
    }
    *(f16x8*)&Bs[srow * LP + skh] =
        *(const f16x8*)((const _Float16*)WT + (size_t)srow * K + k0 + skh);
    __syncthreads();

    f16x8 fa[4], fb[2];
#pragma unroll
    for (int m = 0; m < 4; m++)
      fa[m] = *(f16x8*)&As[(wr * 64 + m * 16 + rrow) * LP + rsel * 8];
#pragma unroll
    for (int n = 0; n < 2; n++)
      fb[n] = *(f16x8*)&Bs[(wc * 32 + n * 16 + rrow) * LP + rsel * 8];
#pragma unroll
    for (int m = 0; m < 4; m++)
#pragma unroll
      for (int n = 0; n < 2; n++)
        acc[m][n] = __builtin_amdgcn_mfma_f32_16x16x32_f16(fa[m], fb[n], acc[m][n], 0, 0, 0);
    __syncthreads();
  }

#pragma unroll
  for (int n = 0; n < 2; n++) {
    int c = wc * 32 + n * 16 + rrow;
#pragma unroll
    for (int m = 0; m < 4; m++) {
      f32x4 v = acc[m][n];
#pragma unroll
      for (int r = 0; r < 4; r++) {
        int row = row0 + wr * 64 + m * 16 + rsel * 4 + r;
        if (row < M) out0[(size_t)row * 128 + c] = __float2half(v[r]);
      }
    }
  }
}

// ---------------- pull-based SpMM (fp16 rows, on-the-fly norm) ----------------

__global__ __launch_bounds__(256) void k_spmm_h(
    const __half* __restrict__ in, const int* __restrict__ rowptr,
    const int* __restrict__ cnt, const int* __restrict__ col,
    const float* __restrict__ dinv,
    const float* __restrict__ bias, __half* __restrict__ out,
    int n, int use_bias, int relu_out) {
  int node = blockIdx.x * 4 + (threadIdx.x >> 6);
  if (node >= n) return;
  int lane = threadIdx.x & 63;

  const __half2* inp = (const __half2*)in;
  float di = dinv[node];
  float2 v = __half22float2(inp[(size_t)node * 64 + lane]);
  float accx = di * v.x;
  float accy = di * v.y;

  int beg = rowptr[node];
  int m = cnt[node];
  int i = 0;
  for (; i + 8 <= m; i += 8) {
    int c[8];
#pragma unroll
    for (int j = 0; j < 8; j++) c[j] = col[beg + i + j];
    float e[8];
#pragma unroll
    for (int j = 0; j < 8; j++) e[j] = dinv[c[j]];
    float2 u[8];
#pragma unroll
    for (int j = 0; j < 8; j++) u[j] = __half22float2(inp[(size_t)c[j] * 64 + lane]);
#pragma unroll
    for (int j = 0; j < 8; j++) { accx += e[j] * u[j].x; accy += e[j] * u[j].y; }
  }
  if (i < m) {
    int c[8];
#pragma unroll
    for (int j = 0; j < 8; j++) c[j] = col[(i + j < m) ? (beg + i + j) : beg];
    float e[8];
#pragma unroll
    for (int j = 0; j < 8; j++) e[j] = (i + j < m) ? dinv[c[j]] : 0.f;
    float2 u[8];
#pragma unroll
    for (int j = 0; j < 8; j++) u[j] = __half22float2(inp[(size_t)c[j] * 64 + lane]);
#pragma unroll
    for (int j = 0; j < 8; j++) { accx += e[j] * u[j].x; accy += e[j] * u[j].y; }
  }
  accx *= di;
  accy *= di;
  if (use_bias) {
    accx += bias[2 * lane];
    accy += bias[2 * lane + 1];
  }
  if (relu_out) {
    accx = fmaxf(accx, 0.f);
    accy = fmaxf(accy, 0.f);
  }
  ((__half2*)(out + (size_t)node * 128))[lane] = __floats2half2_rn(accx, accy);
}

// ---------------- fused SpMM2 + GEMM2 (exact round-14 structure, measured 113.5us) ----------------
// Block = 16 nodes, 4 waves x 4 serialized nodes (variance smoothing at the barrier).
// Phase 1: gather g-rows -> swizzled LDS (4KB). Phase 2: 16x256 MFMA.

__global__ __launch_bounds__(256) void k_spmm_gemm(
    const __half* __restrict__ in, const int* __restrict__ rowptr,
    const int* __restrict__ cnt, const int* __restrict__ col,
    const float* __restrict__ dinv,
    const __half* __restrict__ WcT, const float* __restrict__ bcat,
    float* __restrict__ out0, float* __restrict__ out1, int n) {
  __shared__ _Float16 gt[16 * 128];   // 16 rows x 256B, 16B-chunk XOR-swizzled by row
  const int tid = threadIdx.x;
  const int lane = tid & 63;
  const int w = tid >> 6;
  const __half2* inp = (const __half2*)in;

  for (int q = 0; q < 4; q++) {
    int li = w * 4 + q;
    int node = blockIdx.x * 16 + li;
    float accx = 0.f, accy = 0.f;
    if (node < n) {
      float di = dinv[node];
      float2 v = __half22float2(inp[(size_t)node * 64 + lane]);
      accx = di * v.x;
      accy = di * v.y;
      int beg = rowptr[node];
      int m = cnt[node];
      int i = 0;
      for (; i + 8 <= m; i += 8) {
        int c[8];
#pragma unroll
        for (int j = 0; j < 8; j++) c[j] = col[beg + i + j];
        float e[8];
#pragma unroll
        for (int j = 0; j < 8; j++) e[j] = dinv[c[j]];
        float2 u[8];
#pragma unroll
        for (int j = 0; j < 8; j++) u[j] = __half22float2(inp[(size_t)c[j] * 64 + lane]);
#pragma unroll
        for (int j = 0; j < 8; j++) { accx += e[j] * u[j].x; accy += e[j] * u[j].y; }
      }
      if (i < m) {
        int c[8];
#pragma unroll
        for (int j = 0; j < 8; j++) c[j] = col[(i + j < m) ? (beg + i + j) : beg];
        float e[8];
#pragma unroll
        for (int j = 0; j < 8; j++) e[j] = (i + j < m) ? dinv[c[j]] : 0.f;
        float2 u[8];
#pragma unroll
        for (int j = 0; j < 8; j++) u[j] = __half22float2(inp[(size_t)c[j] * 64 + lane]);
#pragma unroll
        for (int j = 0; j < 8; j++) { accx += e[j] * u[j].x; accy += e[j] * u[j].y; }
      }
      accx *= di;
      accy *= di;
    }
    int slot = (lane >> 2) ^ (li & 7);
    *(__half2*)((char*)gt + li * 256 + slot * 16 + (lane & 3) * 4) =
        __floats2half2_rn(accx, accy);
  }
  __syncthreads();

  const int lr = lane & 15;
  const int lk = lane >> 4;
  f16x8 a[4];
#pragma unroll
  for (int ks = 0; ks < 4; ks++) {
    int slot = (ks * 4 + lk) ^ (lr & 7);
    a[ks] = *(const f16x8*)((const char*)gt + lr * 256 + slot * 16);
  }
#pragma unroll
  for (int ct = 0; ct < 4; ct++) {
    int colg = (w * 4 + ct) * 16 + lr;    // 0..255
    f32x4 acc = (f32x4){0.f, 0.f, 0.f, 0.f};
#pragma unroll
    for (int ks = 0; ks < 4; ks++) {
      f16x8 b = *(const f16x8*)((const _Float16*)WcT + (size_t)colg * 128 + ks * 32 + lk * 8);
      acc = __builtin_amdgcn_mfma_f32_16x16x32_f16(a[ks], b, acc, 0, 0, 0);
    }
    float badd = bcat[colg];
    float* dst = out0;
    int c = colg;
    if (c >= 128) { dst = out1; c -= 128; }
#pragma unroll
    for (int r = 0; r < 4; r++) {
      int node = blockIdx.x * 16 + lk * 4 + r;
      if (node < n) dst[(size_t)node * 128 + c] = acc[r] + badd;
    }
  }
}

// ---------------- launch ----------------

extern "C" void kernel_launch(void* const* d_in, const int* in_sizes, int n_in,
                              void* d_out, int out_size, void* d_ws, size_t ws_size,
                              hipStream_t stream) {
  const float* x   = (const float*)d_in[0];
  const int*   ei  = (const int*)d_in[1];
  const float* W1  = (const float*)d_in[2];
  const float* b1  = (const float*)d_in[3];
  const float* Wmu = (const float*)d_in[4];
  const float* bmu = (const float*)d_in[5];
  const float* Wls = (const float*)d_in[6];
  const float* bls = (const float*)d_in[7];

  int N = in_sizes[0] / 256;
  int E = in_sizes[1] / 2;
  const int* src = ei;
  const int* dst = ei + E;

  int NBINS = (N + 127) >> 7;
  int NBLK  = (E + EPB - 1) / EPB;

  char* ws = (char*)d_ws;
  size_t o = 0;
  auto alloc = [&](size_t b) { size_t c = o; o = (o + b + 511) & ~(size_t)511; return c; };
  int*   cnt       = (int*)(ws + alloc((size_t)N * 4));
  int*   rowptr    = (int*)(ws + alloc((size_t)N * 4));
  float* dinv      = (float*)(ws + alloc((size_t)N * 4));
  int*   binCursor = (int*)(ws + alloc((size_t)NBINS * 4));
  int*   col       = (int*)(ws + alloc((size_t)NBINS * CAP * 4));
  int*   binned    = (int*)(ws + alloc((size_t)NBINS * CAP * 4));
  __half* W1T  = (__half*)(ws + alloc(128 * 256 * 2));
  __half* WcT  = (__half*)(ws + alloc(256 * 128 * 2));
  float*  bcat = (float*)(ws + alloc(256 * 4));
  __half* h0   = (__half*)(ws + alloc((size_t)N * 128 * 2));  // GEMM1 out
  __half* hBuf = (__half*)(ws + alloc((size_t)N * 128 * 2));  // h (relu'd)

  float* outMu = (float*)d_out;
  float* outLs = outMu + (size_t)N * 128;

  // ---- CSR build: reserve-scatter -> fused bin-finish ----
  hipMemsetAsync(binCursor, 0, (size_t)NBINS * 4, stream);
  k_fused_scatter<<<NBLK, 256, 0, stream>>>(src, dst, binCursor, binned, E, NBINS);
  k_bin_finish<<<NBINS, 256, 0, stream>>>(binned, binCursor, cnt, rowptr, dinv, col,
                                          NBINS, N);

  // ---- weights ----
  k_prep_w<<<(2 * 128 * 256 + 256 + 255) / 256, 256, 0, stream>>>(
      W1, Wmu, Wls, bmu, bls, W1T, WcT, bcat);

  // h0 = x @ W1                 [N,128] fp16 (8-wave round-10 skeleton)
  k_gemm_mfma<<<(N + 127) / 128, 512, 0, stream>>>(x, W1T, h0, N, 256);
  // h = relu(A h0 + b1)         [N,128] fp16
  k_spmm_h<<<(N + 3) / 4, 256, 0, stream>>>(h0, rowptr, cnt, col, dinv, b1, hBuf, N, 1, 1);
  // [mu|ls] = (A h) @ [Wmu|Wls] + [bmu|bls]   fused: g stays in LDS (R14 form)
  k_spmm_gemm<<<(N + 15) / 16, 256, 0, stream>>>(
      hBuf, rowptr, cnt, col, dinv, WcT, bcat, outMu, outLs, N);
}